// Round 2
// baseline (766.147 us; speedup 1.0000x reference)
//
#include <hip/hip_runtime.h>

#define NCOL  2048
#define NROW  64
#define NSTEP 1000
#define NTH   256
#define EPT   8   // elements (columns) per thread: 256*8 = 2048

typedef float vf4 __attribute__((ext_vector_type(4)));
typedef float vf2 __attribute__((ext_vector_type(2)));

// One block per row. Row state ping-pongs in LDS; full time loop in-kernel.
// Global trajectory stores are delayed by one step so the vmcnt(0) drain the
// compiler inserts before s_barrier overlaps a full step of compute.
__global__ __launch_bounds__(NTH) void ks_kernel(
    const float* __restrict__ u0,
    const float* __restrict__ c_in,
    const float* __restrict__ alpha_in,
    const float* __restrict__ beta_in,
    float* __restrict__ out)
{
    __shared__ float buf[2][NCOL];

    const int row = blockIdx.x;
    const int tid = threadIdx.x;

    const float c     = c_in[0];
    const float alpha = alpha_in[0];
    const float beta  = beta_in[0];

    const float dt      = 0.01f;
    const float inv2dx  = 0.5f;   // 1/(2*dx), dx=1
    const float invdx2  = 1.0f;   // 1/dx^2
    const float invdx4  = 1.0f;   // 1/dx^4

    // ---- load u0 row into LDS, emit slab 0 (u0 copy) ----
    const float* __restrict__ urow = u0 + (size_t)row * NCOL;
    vf4 v0 = ((const vf4*)urow)[tid * 2 + 0];
    vf4 v1 = ((const vf4*)urow)[tid * 2 + 1];
    ((vf4*)(buf[0]))[tid * 2 + 0] = v0;
    ((vf4*)(buf[0]))[tid * 2 + 1] = v1;

    float* __restrict__ orow0 = out + (size_t)row * NCOL;
    __builtin_nontemporal_store(v0, (vf4*)(orow0) + tid * 2 + 0);
    __builtin_nontemporal_store(v1, (vf4*)(orow0) + tid * 2 + 1);

    const int    base = tid * EPT;
    const size_t slab = (size_t)NROW * NCOL;
    float* outp = out + slab + (size_t)row * NCOL;   // slab 1 row base

    int p = 0;
    vf4 pa, pb;                  // pending (delayed) store payload
    float* pout = nullptr;       // pending store address

    for (int t = 1; t <= NSTEP; ++t) {
        __syncthreads();

        // retire the previous step's store (uniform branch)
        if (t > 1) {
            __builtin_nontemporal_store(pa, (vf4*)(pout));
            __builtin_nontemporal_store(pb, (vf4*)(pout) + 1);
        }

        const float* cur = buf[p];

        // cols [base-2 .. base+9] -> w[0..11]; pairs are even-aligned so no
        // pair straddles the periodic wrap (wrap boundary 2048 is even).
        float w[12];
        #pragma unroll
        for (int i = 0; i < 6; ++i) {
            int idx = (base - 2 + 2 * i) & (NCOL - 1);
            vf2 pr = *(const vf2*)&cur[idx];
            w[2 * i]     = pr.x;
            w[2 * i + 1] = pr.y;
        }

        float nw[EPT];
        #pragma unroll
        for (int i = 0; i < EPT; ++i) {
            float um2 = w[i];
            float um1 = w[i + 1];
            float u   = w[i + 2];
            float up1 = w[i + 3];
            float up2 = w[i + 4];
            float u_x    = (up1 - um1) * inv2dx;
            float u_xx   = (up1 - 2.0f * u + um1) * invdx2;
            float u_xxxx = (up2 - 4.0f * up1 + 6.0f * u - 4.0f * um1 + um2) * invdx4;
            nw[i] = u + dt * (-c * u * u_x - alpha * u_xx - beta * u_xxxx);
        }

        float* nxt = buf[1 - p];
        vf4 na = { nw[0], nw[1], nw[2], nw[3] };
        vf4 nb = { nw[4], nw[5], nw[6], nw[7] };
        *(vf4*)&nxt[base]     = na;
        *(vf4*)&nxt[base + 4] = nb;

        pa   = na;
        pb   = nb;
        pout = outp + base;
        outp += slab;
        p ^= 1;
    }

    // retire the final step's store
    __builtin_nontemporal_store(pa, (vf4*)(pout));
    __builtin_nontemporal_store(pb, (vf4*)(pout) + 1);
}

extern "C" void kernel_launch(void* const* d_in, const int* in_sizes, int n_in,
                              void* d_out, int out_size, void* d_ws, size_t ws_size,
                              hipStream_t stream) {
    const float* u0    = (const float*)d_in[0];
    const float* c     = (const float*)d_in[1];
    const float* alpha = (const float*)d_in[2];
    const float* beta  = (const float*)d_in[3];
    float* out = (float*)d_out;

    ks_kernel<<<NROW, NTH, 0, stream>>>(u0, c, alpha, beta, out);
}